// Round 19
// baseline (173.220 us; speedup 1.0000x reference)
//
#include <hip/hip_runtime.h>
#include <math.h>

#define NH 16
#define NKV 8
#define HDIM 128
#define SEQ 2048
#define DMODEL 2048

typedef int   v4i __attribute__((ext_vector_type(4)));
typedef float v4f __attribute__((ext_vector_type(4)));
typedef _Float16 v8h __attribute__((ext_vector_type(8)));

static constexpr float SM_SCALE = 0.08838834764831843f; // 128**-0.5

#define GLOBP(p) (__attribute__((address_space(1))) void*)(p)
#define LDSP(p)  (__attribute__((address_space(3))) void*)(p)
#define ASYNC16(g, l) __builtin_amdgcn_global_load_lds(GLOBP(g), LDSP(l), 16, 0, 0)

// Fragment-tiled i8 layout for X[R][K] (R%16==0, K%64==0):
// frag (r>>4, k>>6) is 1024B; within: byte = ((k>>4)&3)*256 + (r&15)*16 + (k&15).

__device__ __forceinline__ unsigned short f2h_bits(float x) {
    _Float16 h = (_Float16)x;               // RN, exact for small ints
    return __builtin_bit_cast(unsigned short, h);
}

// ---------------- merged per-row int8 quant (5 inputs) + rope table ----------------
__global__ __launch_bounds__(256) void quant_rope_k(const float* __restrict__ hidden,
        const float* __restrict__ Wq, const float* __restrict__ Wk,
        const float* __restrict__ Wv, const float* __restrict__ Wo,
        const int* __restrict__ pos_ids,
        signed char* __restrict__ out, float* __restrict__ scale,
        float* __restrict__ ct, float* __restrict__ st) {
    int p = blockIdx.x;
    if (p >= 512) {
        int t = (p - 512) * 4 + (threadIdx.x >> 6);
        int fi = threadIdx.x & 63;
        float inv = 1.0f / (float)pow(1.0e6, (double)fi / 64.0);
        float fr = (float)pos_ids[t] * inv;
        float sn, c;
        sincosf(fr, &sn, &c);
        ct[t * 64 + fi] = c;
        st[t * 64 + fi] = sn;
        return;
    }
    int row0g = p * 16;
    const float* in; int lr0;
    if (row0g < 2048)      { in = hidden; lr0 = row0g; }
    else if (row0g < 4096) { in = Wq; lr0 = row0g - 2048; }
    else if (row0g < 5120) { in = Wk; lr0 = row0g - 4096; }
    else if (row0g < 6144) { in = Wv; lr0 = row0g - 5120; }
    else                   { in = Wo; lr0 = row0g - 6144; }
    const int cols = 2048;
    int tid = threadIdx.x;
    __shared__ float srow[16];
    int r = tid >> 4, l16 = tid & 15;
    const float4* x4 = (const float4*)(in + (size_t)(lr0 + r) * cols);
    float amax = 0.f;
    for (int c4 = l16; c4 < (cols >> 2); c4 += 16) {
        float4 v = x4[c4];
        amax = fmaxf(amax, fmaxf(fmaxf(fabsf(v.x), fabsf(v.y)),
                                 fmaxf(fabsf(v.z), fabsf(v.w))));
    }
#pragma unroll
    for (int m = 1; m <= 8; m <<= 1) amax = fmaxf(amax, __shfl_xor(amax, m));
    if (l16 == 0) {
        float s = fmaxf(amax / 127.0f, 1e-8f);
        srow[r] = s;
        scale[row0g + r] = s;
    }
    __syncthreads();
    int total = (cols >> 4) * 16;
    size_t obase = (size_t)p * 32768;
    for (int idx = tid; idx < total; idx += 256) {
        int f = idx >> 6, q = (idx >> 4) & 3, rr = idx & 15;
        const float* src = in + (size_t)(lr0 + rr) * cols + f * 64 + q * 16;
        float s = srow[rr];
        unsigned int wds[4];
#pragma unroll
        for (int g = 0; g < 4; ++g) {
            float4 v = *(const float4*)(src + g * 4);
            int b0 = (int)fminf(fmaxf(rintf(v.x / s), -127.f), 127.f);
            int b1 = (int)fminf(fmaxf(rintf(v.y / s), -127.f), 127.f);
            int b2 = (int)fminf(fmaxf(rintf(v.z / s), -127.f), 127.f);
            int b3 = (int)fminf(fmaxf(rintf(v.w / s), -127.f), 127.f);
            wds[g] = (b0 & 255) | ((b1 & 255) << 8) | ((b2 & 255) << 16) | ((b3 & 255) << 24);
        }
        *(uint4*)(out + obase + (size_t)idx * 16) =
            make_uint4(wds[0], wds[1], wds[2], wds[3]);
    }
}

// ---------------- fused max-aware split-K combine + row quant (attn raw -> a_i8) ----------
__global__ __launch_bounds__(256) void row_quant_red_k(const float* __restrict__ attn2,
        const float* __restrict__ pp, const float* __restrict__ zb,
        signed char* __restrict__ out, float* __restrict__ scale) {
    int row0 = blockIdx.x * 16;
    int tid = threadIdx.x;
    __shared__ float srow[16];
    __shared__ float4 spvt[16][17];     // (w0, w1, spv, -)
    {
        int r = tid >> 4, h = tid & 15;
        int row = row0 + r;
        int t32 = row >> 6, rr = row & 63;
        const float2* zb2 = (const float2*)zb;
        float2 a0 = zb2[(((size_t)h * 32 + t32) * 2 + 0) * 64 + rr];
        float2 a1 = zb2[(((size_t)h * 32 + t32) * 2 + 1) * 64 + rr];
        float M = fmaxf(a0.x, a1.x);
        float w0 = __expf(a0.x - M), w1 = __expf(a1.x - M);
        float Zt = a0.y * w0 + a1.y * w1;
        float spv = fmaxf((1.0f / Zt) / 127.0f, 1e-8f);
        spvt[r][h] = make_float4(w0, w1, spv, 0.f);
    }
    __syncthreads();
    int r = tid >> 4, l16 = tid & 15;
    int row = row0 + r;
    const float4* x4 = (const float4*)(attn2 + (size_t)row * 2048);
    size_t ppr = ((size_t)(row >> 6) * 64 + (row & 63)) * 128;
    float amax = 0.f;
    for (int c4 = l16; c4 < 512; c4 += 16) {
        float4 v = x4[c4];
        int h = c4 >> 5;
        int j = (c4 & 31) * 4;
        float4 pv = *(const float4*)&pp[(size_t)h * 32 * 64 * 128 + ppr + j];
        float4 wz = spvt[r][h];
        v.x = (v.x * wz.x + pv.x * wz.y) * wz.z;
        v.y = (v.y * wz.x + pv.y * wz.y) * wz.z;
        v.z = (v.z * wz.x + pv.z * wz.y) * wz.z;
        v.w = (v.w * wz.x + pv.w * wz.y) * wz.z;
        amax = fmaxf(amax, fmaxf(fmaxf(fabsf(v.x), fabsf(v.y)),
                                 fmaxf(fabsf(v.z), fabsf(v.w))));
    }
#pragma unroll
    for (int m = 1; m <= 8; m <<= 1) amax = fmaxf(amax, __shfl_xor(amax, m));
    if (l16 == 0) {
        float s = fmaxf(amax / 127.0f, 1e-8f);
        srow[r] = s;
        scale[row0 + r] = s;
    }
    __syncthreads();
    size_t obase = ((size_t)(row0 >> 4) * 32) << 10;
    for (int idx = tid; idx < 2048; idx += 256) {
        int f = idx >> 6, q = (idx >> 4) & 3, rr16 = idx & 15;
        int rowb = row0 + rr16;
        int colb = f * 64 + q * 16;
        const float* src = attn2 + (size_t)rowb * 2048 + colb;
        float s = srow[rr16];
        int h = f >> 1;
        float4 wz = spvt[rr16][h];
        size_t ppb = (size_t)h * 32 * 64 * 128
                   + ((size_t)(rowb >> 6) * 64 + (rowb & 63)) * 128 + (colb & 127);
        unsigned int wds[4];
#pragma unroll
        for (int g = 0; g < 4; ++g) {
            float4 v = *(const float4*)(src + g * 4);
            float4 pv = *(const float4*)&pp[ppb + g * 4];
            v.x = (v.x * wz.x + pv.x * wz.y) * wz.z;
            v.y = (v.y * wz.x + pv.y * wz.y) * wz.z;
            v.z = (v.z * wz.x + pv.z * wz.y) * wz.z;
            v.w = (v.w * wz.x + pv.w * wz.y) * wz.z;
            int b0 = (int)fminf(fmaxf(rintf(v.x / s), -127.f), 127.f);
            int b1 = (int)fminf(fmaxf(rintf(v.y / s), -127.f), 127.f);
            int b2 = (int)fminf(fmaxf(rintf(v.z / s), -127.f), 127.f);
            int b3 = (int)fminf(fmaxf(rintf(v.w / s), -127.f), 127.f);
            wds[g] = (b0 & 255) | ((b1 & 255) << 8) | ((b2 & 255) << 16) | ((b3 & 255) << 24);
        }
        *(uint4*)(out + obase + (size_t)idx * 16) =
            make_uint4(wds[0], wds[1], wds[2], wds[3]);
    }
}

// ---------------- O-projection GEMM: 128x64 tile -> 512 blocks ----------------
__global__ __launch_bounds__(256, 3) void gemm_o_k(const signed char* __restrict__ A,
        const float* __restrict__ sa, const signed char* __restrict__ B,
        const float* __restrict__ sb, float* __restrict__ C, int M, int N, int K) {
    __shared__ __align__(16) signed char lsA[3][8192];
    __shared__ __align__(16) signed char lsB[3][4096];
    int tid = threadIdx.x;
    int w = tid >> 6, l = tid & 63;
    int wr = w >> 1, wc = w & 1;
    int lrow = l & 15;
    int m0 = blockIdx.y * 128, n0 = blockIdx.x * 64;
    int kb6 = K >> 6;
    v4i acc[4][2];
#pragma unroll
    for (int i = 0; i < 4; ++i)
#pragma unroll
        for (int j = 0; j < 2; ++j) acc[i][j] = (v4i){0, 0, 0, 0};

    auto stage = [&](int buf, int k6) {
#pragma unroll
        for (int a = 0; a < 2; ++a) {
            int f = a * 4 + w;
            ASYNC16(A + (((size_t)(((m0 >> 4) + f) * kb6 + k6)) << 10) + l * 16,
                    lsA[buf] + f * 1024);
        }
        ASYNC16(B + (((size_t)(((n0 >> 4) + w) * kb6 + k6)) << 10) + l * 16,
                lsB[buf] + w * 1024);
    };

    stage(0, 0);
    if (kb6 > 1) {
        stage(1, 1);
        asm volatile("s_waitcnt vmcnt(3)" ::: "memory");
    } else {
        asm volatile("s_waitcnt vmcnt(0)" ::: "memory");
    }
    __builtin_amdgcn_s_barrier();
    for (int t = 0; t < kb6; ++t) {
        if (t + 2 < kb6) stage((t + 2) % 3, t + 2);
        int cur = t % 3;
        v4i af[4], bf[2];
#pragma unroll
        for (int i = 0; i < 4; ++i) af[i] = *(const v4i*)(lsA[cur] + (wr * 4 + i) * 1024 + l * 16);
#pragma unroll
        for (int j = 0; j < 2; ++j) bf[j] = *(const v4i*)(lsB[cur] + (wc * 2 + j) * 1024 + l * 16);
#pragma unroll
        for (int i = 0; i < 4; ++i)
#pragma unroll
            for (int j = 0; j < 2; ++j)
                acc[i][j] = __builtin_amdgcn_mfma_i32_16x16x64_i8(af[i], bf[j], acc[i][j], 0, 0, 0);
        if (t + 2 < kb6) asm volatile("s_waitcnt vmcnt(3)" ::: "memory");
        else             asm volatile("s_waitcnt vmcnt(0)" ::: "memory");
        __builtin_amdgcn_s_barrier();
    }
    int r0 = m0 + wr * 64, c0 = n0 + wc * 32;
    int lg = l >> 4;
    float sbv[2];
#pragma unroll
    for (int j = 0; j < 2; ++j) sbv[j] = sb[c0 + j * 16 + lrow];
#pragma unroll
    for (int i = 0; i < 4; ++i) {
        float4 s4 = *(const float4*)(sa + r0 + i * 16 + lg * 4);
        float sav[4] = {s4.x, s4.y, s4.z, s4.w};
#pragma unroll
        for (int j = 0; j < 2; ++j) {
#pragma unroll
            for (int reg = 0; reg < 4; ++reg) {
                int rr = r0 + i * 16 + lg * 4 + reg;
                C[(size_t)rr * N + c0 + j * 16 + lrow] = (float)acc[i][j][reg] * (sav[reg] * sbv[j]);
            }
        }
    }
}

// ---------------- QKV GEMM, BM=64 -> 1024 blocks (~4/CU), fused epilogue ----------
// LDS union: staging A 3x4K + B 3x8K = 36KB (main) / fp32 tile [64][132]+srow (epilogue).
__global__ __launch_bounds__(256, 2) void gemm_qkv_k(const signed char* __restrict__ A,
        const float* __restrict__ sa, const signed char* __restrict__ B,
        const float* __restrict__ sb,
        const float* __restrict__ qw, const float* __restrict__ kw,
        const float* __restrict__ ct, const float* __restrict__ st,
        signed char* __restrict__ q_i8, float* __restrict__ sq,
        signed char* __restrict__ k_i8, float* __restrict__ sk,
        unsigned short* __restrict__ vtT) {
    __shared__ __align__(16) char smem[36864];
    signed char (*lsA)[4096] = (signed char(*)[4096])smem;           // 12 KB
    signed char (*lsB)[8192] = (signed char(*)[8192])(smem + 12288); // 24 KB
    float (*tile)[132] = (float(*)[132])smem;                        // 33.8 KB (epilogue)
    float* srow = (float*)(smem + 33792);                            // 256 B
    int tid = threadIdx.x;
    int w = tid >> 6, l = tid & 63;
    int wr = w >> 1, wc = w & 1;
    int lrow = l & 15, lg = l >> 4;
    int m0 = blockIdx.y * 64, n0 = blockIdx.x * 128;
    const int kb6 = 32;                               // K = 2048
    v4i acc[2][4];
#pragma unroll
    for (int i = 0; i < 2; ++i)
#pragma unroll
        for (int j = 0; j < 4; ++j) acc[i][j] = (v4i){0, 0, 0, 0};

    auto stage = [&](int buf, int k6) {   // 3 ASYNC16 / wave
        ASYNC16(A + (((size_t)(((m0 >> 4) + w) * kb6 + k6)) << 10) + l * 16,
                lsA[buf] + w * 1024);
#pragma unroll
        for (int a = 0; a < 2; ++a) {
            int f = a * 4 + w;
            ASYNC16(B + (((size_t)(((n0 >> 4) + f) * kb6 + k6)) << 10) + l * 16,
                    lsB[buf] + f * 1024);
        }
    };

    stage(0, 0);
    stage(1, 1);
    asm volatile("s_waitcnt vmcnt(3)" ::: "memory");
    __builtin_amdgcn_s_barrier();
    for (int t = 0; t < kb6; ++t) {
        if (t + 2 < kb6) stage((t + 2) % 3, t + 2);
        int cur = t % 3;
        v4i af[2], bf[4];
#pragma unroll
        for (int i = 0; i < 2; ++i) af[i] = *(const v4i*)(lsA[cur] + (wr * 2 + i) * 1024 + l * 16);
#pragma unroll
        for (int j = 0; j < 4; ++j) bf[j] = *(const v4i*)(lsB[cur] + (wc * 4 + j) * 1024 + l * 16);
#pragma unroll
        for (int i = 0; i < 2; ++i)
#pragma unroll
            for (int j = 0; j < 4; ++j)
                acc[i][j] = __builtin_amdgcn_mfma_i32_16x16x64_i8(af[i], bf[j], acc[i][j], 0, 0, 0);
        if (t + 2 < kb6) asm volatile("s_waitcnt vmcnt(3)" ::: "memory");
        else             asm volatile("s_waitcnt vmcnt(0)" ::: "memory");
        __builtin_amdgcn_s_barrier();
    }
    // ---- scaled fp32 tile -> LDS (staging dead after final barrier) ----
    {
        int c0 = n0 + wc * 64;
        float sbv[4];
#pragma unroll
        for (int j = 0; j < 4; ++j) sbv[j] = sb[c0 + j * 16 + lrow];
#pragma unroll
        for (int i = 0; i < 2; ++i) {
            float4 s4 = *(const float4*)(sa + m0 + wr * 32 + i * 16 + lg * 4);
            float sav[4] = {s4.x, s4.y, s4.z, s4.w};
#pragma unroll
            for (int j = 0; j < 4; ++j)
#pragma unroll
                for (int reg = 0; reg < 4; ++reg)
                    tile[wr * 32 + i * 16 + lg * 4 + reg][wc * 64 + j * 16 + lrow] =
                        (float)acc[i][j][reg] * (sav[reg] * sbv[j]);
        }
    }
    __syncthreads();
    int slot = n0 >> 7;
    if (slot < 24) {
        const float* wn = (slot < 16) ? qw : kw;
        signed char* dst8 = (slot < 16) ? q_i8 + (size_t)slot * (SEQ * 128)
                                        : k_i8 + (size_t)(slot - 16) * (SEQ * 128);
        float* sdst = (slot < 16) ? sq + (size_t)slot * SEQ : sk + (size_t)(slot - 16) * SEQ;
        float wn0 = wn[l], wn1 = wn[l + 64];
        for (int it = 0; it < 16; ++it) {
            int tl = it * 4 + w;
            int t = m0 + tl;
            float x0 = tile[tl][l];
            float x1 = tile[tl][l + 64];
            float ss = x0 * x0 + x1 * x1;
#pragma unroll
            for (int m = 1; m <= 32; m <<= 1) ss += __shfl_xor(ss, m);
            float rs = 1.0f / sqrtf(ss / 128.0f + 1e-6f);
            x0 = (x0 * rs) * wn0;
            x1 = (x1 * rs) * wn1;
            float cth = ct[t * 64 + l];
            float sth = st[t * 64 + l];
            float nx0 = x0 * cth - x1 * sth;
            float nx1 = x1 * cth + x0 * sth;
            float amax = fmaxf(fabsf(nx0), fabsf(nx1));
#pragma unroll
            for (int m = 1; m <= 32; m <<= 1) amax = fmaxf(amax, __shfl_xor(amax, m));
            float s = fmaxf(amax / 127.0f, 1e-8f);
            float q0 = fminf(fmaxf(rintf(nx0 / s), -127.f), 127.f);
            float q1 = fminf(fmaxf(rintf(nx1 / s), -127.f), 127.f);
            size_t ta0 = (size_t)(((t >> 4) * 2) << 10)
                       + (size_t)((((l >> 4) & 3) << 8) + ((t & 15) << 4) + (l & 15));
            dst8[ta0] = (signed char)(int)q0;
            dst8[ta0 + 1024] = (signed char)(int)q1;
            if (l == 0) sdst[t] = s;
        }
    } else {
        int kv = slot - 24;
        for (int it = 0; it < 16; ++it) {
            int tl = it * 4 + w;
            float x0 = tile[tl][l];
            float x1 = tile[tl][l + 64];
            float amax = fmaxf(fabsf(x0), fabsf(x1));
#pragma unroll
            for (int m = 1; m <= 32; m <<= 1) amax = fmaxf(amax, __shfl_xor(amax, m));
            if (l == 0) srow[tl] = fmaxf(amax / 127.0f, 1e-8f);
        }
        __syncthreads();
        int d = tid >> 1, th = (tid & 1) * 32;
        size_t base = (size_t)kv * (SEQ * 128);
        int kb = m0 >> 6;
#pragma unroll
        for (int j = 0; j < 32; j += 2) {
            int t64 = th + j;
            float s0 = srow[t64], s1 = srow[t64 + 1];
            float a = fminf(fmaxf(rintf(tile[t64][d] / s0), -127.f), 127.f) * s0;
            float b = fminf(fmaxf(rintf(tile[t64 + 1][d] / s1), -127.f), 127.f) * s1;
            unsigned int ua = f2h_bits(a), ub = f2h_bits(b);
            int off = kb * 8192 + ((d >> 4) * 2 + ((t64 >> 5) & 1)) * 512
                    + (((d & 15) + (((t64 >> 3) & 3) << 4)) << 3) + (t64 & 7);
            *(unsigned int*)(vtT + base + off) = ua | (ub << 16);
        }
    }
}

// ---------------- attention: online-softmax flash, 32-row sub-tiles -> 1024 blocks ----------
__global__ __launch_bounds__(256, 2) void attn_k(const signed char* __restrict__ q_i8,
        const float* __restrict__ sq, const signed char* __restrict__ k_i8,
        const float* __restrict__ sk, const unsigned short* __restrict__ vtT,
        float* __restrict__ attn2, float* __restrict__ pp, float* __restrict__ zb) {
    __shared__ __align__(16) unsigned short vlds[2][8192];  // 32 KB
    __shared__ __align__(16) signed char klds[8192];        // 8 KB
    __shared__ __align__(16) unsigned short plds[4096];     // 8 KB wave-private
    int bx = blockIdx.x, hp = blockIdx.y;
    int qs = 63 - (bx >> 1), c = bx & 1;
    int qb = qs >> 1;                    // 64-row tile index (for pp/zb indexing)
    int q0s = qs * 32;
    int hsp = (qb + 2) >> 1;
    int kb0 = c ? hsp : 0;
    int kb1 = c ? (qb + 1) : hsp;
    int tid = threadIdx.x, w = tid >> 6, l = tid & 63;
    int lrow = l & 15, lg = l >> 4;
    int hh = hp * 2 + (w >> 1);          // this wave's head
    int wrow = (w & 1) * 16;             // row offset within the 32-row sub-tile
    int rrb = (qs & 1) * 32 + wrow;      // row offset within the 64-row tile

    if (kb0 >= kb1) {                    // qb==0 (qs 0,1), c==1: sentinel
        if (lrow == 0) {
            float2* zb2 = (float2*)zb;
            size_t z = (((size_t)hh * 32 + qb) * 2 + c) * 64;
#pragma unroll
            for (int reg = 0; reg < 4; ++reg)
                zb2[z + rrb + lg * 4 + reg] = make_float2(-1e30f, 0.f);
        }
        return;
    }

    const signed char* qt = q_i8 + (size_t)hh * (SEQ * 128)
                          + ((size_t)((qs * 2 + (w & 1)) * 2) << 10) + l * 16;
    v4i qf0 = *(const v4i*)(qt), qf1 = *(const v4i*)(qt + 1024);
    float4 s4 = *(const float4*)(sq + (size_t)hh * SEQ + q0s + wrow + lg * 4);
    float sqr[4] = {s4.x, s4.y, s4.z, s4.w};

    const signed char* kbase = k_i8 + (size_t)hp * (SEQ * 128);
    const float* skb = sk + (size_t)hp * SEQ;
    const unsigned short* vt = vtT + (size_t)hp * (SEQ * 128);

    auto issueV = [&](int kb) {     // 4 ASYNC16 / wave into vlds[kb&1]
        unsigned short* vb = &vlds[kb & 1][0];
#pragma unroll
        for (int a = 0; a < 4; ++a) {
            int fv = a * 4 + w;
            ASYNC16(vt + (size_t)kb * 8192 + fv * 512 + l * 8, vb + fv * 512);
        }
    };
    auto issueK = [&](int kb) {     // 2 ASYNC16 / wave into klds
#pragma unroll
        for (int a = 0; a < 2; ++a) {
            int f = a * 4 + w;
            ASYNC16(kbase + ((size_t)(kb * 8 + f) << 10) + l * 16, klds + f * 1024);
        }
    };

    v4f acc[8];
#pragma unroll
    for (int jd = 0; jd < 8; ++jd) acc[jd] = (v4f){0.f, 0.f, 0.f, 0.f};
    float zt[4] = {0.f, 0.f, 0.f, 0.f};
    float mr[4];
#pragma unroll
    for (int r = 0; r < 4; ++r) mr[r] = -1e30f;

    issueK(kb0);
    issueV(kb0);
    asm volatile("s_waitcnt vmcnt(0)" ::: "memory");
    __builtin_amdgcn_s_barrier();

    for (int kb = kb0; kb < kb1; ++kb) {
        int k0 = kb * 64;
        if (kb + 1 < kb1) issueV(kb + 1);
        v4i ka[8];
#pragma unroll
        for (int f = 0; f < 8; ++f)
            ka[f] = *(const v4i*)(klds + f * 1024 + l * 16);
        float skc[4];
#pragma unroll
        for (int j = 0; j < 4; ++j) skc[j] = skb[k0 + j * 16 + lrow];
        v4i sci[4];
#pragma unroll
        for (int j = 0; j < 4; ++j) {
            v4i z = {0, 0, 0, 0};
            v4i t0 = __builtin_amdgcn_mfma_i32_16x16x64_i8(qf0, ka[j * 2], z, 0, 0, 0);
            sci[j] = __builtin_amdgcn_mfma_i32_16x16x64_i8(qf1, ka[j * 2 + 1], t0, 0, 0, 0);
        }
        __builtin_amdgcn_s_barrier();
        if (kb + 1 < kb1) issueK(kb + 1);       // overlaps softmax + PV below
        float sv[4][4];
        float tm[4];
#pragma unroll
        for (int reg = 0; reg < 4; ++reg) tm[reg] = -1e30f;
#pragma unroll
        for (int reg = 0; reg < 4; ++reg) {
            int r = q0s + wrow + lg * 4 + reg;
#pragma unroll
            for (int j = 0; j < 4; ++j) {
                int cc = j * 16 + lrow;
                bool ok = (k0 + cc <= r);
                float ss = skc[j] * SM_SCALE;
                sv[reg][j] = ok ? ((float)sci[j][reg] * sqr[reg]) * ss : -1e30f;
                tm[reg] = fmaxf(tm[reg], sv[reg][j]);
            }
        }
#pragma unroll
        for (int reg = 0; reg < 4; ++reg) {
#pragma unroll
            for (int mask = 1; mask <= 8; mask <<= 1)
                tm[reg] = fmaxf(tm[reg], __shfl_xor(tm[reg], mask));
        }
        float ef[4];
#pragma unroll
        for (int reg = 0; reg < 4; ++reg) {
            float mn = fmaxf(mr[reg], tm[reg]);
            ef[reg] = __expf(mr[reg] - mn);
            mr[reg] = mn;
            zt[reg] *= ef[reg];
        }
        v4f efv = {ef[0], ef[1], ef[2], ef[3]};
#pragma unroll
        for (int jd = 0; jd < 8; ++jd) acc[jd] *= efv;
#pragma unroll
        for (int reg = 0; reg < 4; ++reg) {
            int rq = lg * 4 + reg;
#pragma unroll
            for (int j = 0; j < 4; ++j) {
                int cc = j * 16 + lrow;
                float pd = 0.f;
                float s = sv[reg][j];
                if (s > -5e29f) {
                    float e = __expf(s - mr[reg]);
                    zt[reg] += e;
                    pd = fminf(rintf(127.0f * e), 127.f);
                }
                plds[(w * 2 + (cc >> 5)) * 512 + (rq + 16 * ((cc >> 3) & 3)) * 8 + (cc & 7)] =
                    f2h_bits(pd);
            }
        }
        v8h pf0 = *(const v8h*)(plds + (w * 2 + 0) * 512 + l * 8);
        v8h pf1 = *(const v8h*)(plds + (w * 2 + 1) * 512 + l * 8);
        const unsigned short* vb = &vlds[kb & 1][0];
#pragma unroll
        for (int jd = 0; jd < 8; ++jd) {
            v8h vh0 = *(const v8h*)(vb + (jd * 2 + 0) * 512 + l * 8);
            v8h vh1 = *(const v8h*)(vb + (jd * 2 + 1) * 512 + l * 8);
            v4f t = acc[jd];
            t = __builtin_amdgcn_mfma_f32_16x16x32_f16(pf0, vh0, t, 0, 0, 0);
            t = __builtin_amdgcn_mfma_f32_16x16x32_f16(pf1, vh1, t, 0, 0, 0);
            acc[jd] = t;
        }
        asm volatile("s_waitcnt vmcnt(0)" ::: "memory");
        __builtin_amdgcn_s_barrier();
    }
#pragma unroll
    for (int reg = 0; reg < 4; ++reg) {
#pragma unroll
        for (int mask = 1; mask <= 8; mask <<= 1)
            zt[reg] += __shfl_xor(zt[reg], mask);
    }
    if (c == 0) {
#pragma unroll
        for (int jd = 0; jd < 8; ++jd)
#pragma unroll
            for (int reg = 0; reg < 4; ++reg) {
                int r = q0s + wrow + lg * 4 + reg;
                attn2[(size_t)r * DMODEL + hh * HDIM + jd * 16 + lrow] = acc[jd][reg];
            }
    } else {
#pragma unroll
        for (int jd = 0; jd < 8; ++jd)
#pragma unroll
            for (int reg = 0; reg < 4; ++reg) {
                int rr = rrb + lg * 4 + reg;
                pp[(((size_t)hh * 32 + qb) * 64 + rr) * 128 + jd * 16 + lrow] = acc[jd][reg];
            }
    }
    if (lrow == 0) {
        float2* zb2 = (float2*)zb;
        size_t z = (((size_t)hh * 32 + qb) * 2 + c) * 64;
#pragma unroll
        for (int reg = 0; reg < 4; ++reg)
            zb2[z + rrb + lg * 4 + reg] = make_float2(mr[reg], zt[reg]);
    }
}

extern "C" void kernel_launch(void* const* d_in, const int* in_sizes, int n_in,
                              void* d_out, int out_size, void* d_ws, size_t ws_size,
                              hipStream_t stream) {
    (void)in_sizes; (void)n_in; (void)out_size; (void)ws_size;
    const float* hidden = (const float*)d_in[0];
    const float* Wq = (const float*)d_in[1];
    const float* Wk = (const float*)d_in[2];
    const float* Wv = (const float*)d_in[3];
    const float* Wo = (const float*)d_in[4];
    const float* qw = (const float*)d_in[5];
    const float* kw = (const float*)d_in[6];
    const int* pos = (const int*)d_in[7];
    float* out = (float*)d_out;
    char* ws = (char*)d_ws;

    const size_t MB = 1024 * 1024;
    signed char* x_i8  = (signed char*)(ws);            // 16 MB tiled i8 block (x,wq,wk,wv,wo)
    signed char* wq_i8 = (signed char*)(ws + 4 * MB);
    signed char* wo_i8 = (signed char*)(ws + 12 * MB);
    signed char* q_i8  = (signed char*)(ws + 16 * MB);  // 4 MB (attn-tiled)
    signed char* k_i8  = (signed char*)(ws + 20 * MB);  // 2 MB (attn-tiled)
    float* sx  = (float*)(ws + 22 * MB);                // scales
    float* swq = sx + 2048;
    float* swo = sx + 6144;
    float* sq  = sx + 8192;                             // 16*2048
    float* sk  = sq + NH * SEQ;                         // 8*2048
    float* sa  = sk + NKV * SEQ;                        // 2048
    float* ct  = (float*)(ws + 22 * MB + 512 * 1024);   // 512 KB
    float* st  = (float*)(ws + 22 * MB + 1024 * 1024);  // 512 KB
    unsigned short* vtT = (unsigned short*)(ws + 24 * MB); // 4 MB
    float* zb    = (float*)(ws + 28 * MB);              // 512 KB (float2 m,Z per row/chunk)
    float* attn2 = (float*)(ws + 30 * MB);              // 16 MB (chunk-0 raw accs)
    float* pp    = (float*)(ws + 46 * MB);              // 16 MB (chunk-1 raw accs)
    signed char* a_i8 = x_i8;

    quant_rope_k<<<1024, 256, 0, stream>>>(hidden, Wq, Wk, Wv, Wo, pos, x_i8, sx, ct, st);

    gemm_qkv_k<<<dim3(32, 32), 256, 0, stream>>>(x_i8, sx, wq_i8, swq, qw, kw, ct, st,
                                                 q_i8, sq, k_i8, sk, vtT);

    attn_k<<<dim3(128, 8), 256, 0, stream>>>(q_i8, sq, k_i8, sk, vtT, attn2, pp, zb);

    row_quant_red_k<<<128, 256, 0, stream>>>(attn2, pp, zb, a_i8, sa);
    gemm_o_k<<<dim3(32, 16), 256, 0, stream>>>(a_i8, sa, wo_i8, swo, out, 2048, 2048, 2048);
}

// Round 20
// 170.375 us; speedup vs baseline: 1.0167x; 1.0167x over previous
//
#include <hip/hip_runtime.h>
#include <math.h>

#define NH 16
#define NKV 8
#define HDIM 128
#define SEQ 2048
#define DMODEL 2048

typedef int   v4i __attribute__((ext_vector_type(4)));
typedef float v4f __attribute__((ext_vector_type(4)));
typedef _Float16 v8h __attribute__((ext_vector_type(8)));

static constexpr float SM_SCALE = 0.08838834764831843f; // 128**-0.5

#define GLOBP(p) (__attribute__((address_space(1))) void*)(p)
#define LDSP(p)  (__attribute__((address_space(3))) void*)(p)
#define ASYNC16(g, l) __builtin_amdgcn_global_load_lds(GLOBP(g), LDSP(l), 16, 0, 0)

// Fragment-tiled i8 layout for X[R][K] (R%16==0, K%64==0):
// frag (r>>4, k>>6) is 1024B; within: byte = ((k>>4)&3)*256 + (r&15)*16 + (k&15).

__device__ __forceinline__ unsigned short f2h_bits(float x) {
    _Float16 h = (_Float16)x;               // RN, exact for small ints
    return __builtin_bit_cast(unsigned short, h);
}

// ---------------- merged per-row int8 quant (5 inputs) + rope table ----------------
__global__ __launch_bounds__(256) void quant_rope_k(const float* __restrict__ hidden,
        const float* __restrict__ Wq, const float* __restrict__ Wk,
        const float* __restrict__ Wv, const float* __restrict__ Wo,
        const int* __restrict__ pos_ids,
        signed char* __restrict__ out, float* __restrict__ scale,
        float* __restrict__ ct, float* __restrict__ st) {
    int p = blockIdx.x;
    if (p >= 512) {
        int t = (p - 512) * 4 + (threadIdx.x >> 6);
        int fi = threadIdx.x & 63;
        float inv = 1.0f / (float)pow(1.0e6, (double)fi / 64.0);
        float fr = (float)pos_ids[t] * inv;
        float sn, c;
        sincosf(fr, &sn, &c);
        ct[t * 64 + fi] = c;
        st[t * 64 + fi] = sn;
        return;
    }
    int row0g = p * 16;
    const float* in; int lr0;
    if (row0g < 2048)      { in = hidden; lr0 = row0g; }
    else if (row0g < 4096) { in = Wq; lr0 = row0g - 2048; }
    else if (row0g < 5120) { in = Wk; lr0 = row0g - 4096; }
    else if (row0g < 6144) { in = Wv; lr0 = row0g - 5120; }
    else                   { in = Wo; lr0 = row0g - 6144; }
    const int cols = 2048;
    int tid = threadIdx.x;
    __shared__ float srow[16];
    int r = tid >> 4, l16 = tid & 15;
    const float4* x4 = (const float4*)(in + (size_t)(lr0 + r) * cols);
    float amax = 0.f;
    for (int c4 = l16; c4 < (cols >> 2); c4 += 16) {
        float4 v = x4[c4];
        amax = fmaxf(amax, fmaxf(fmaxf(fabsf(v.x), fabsf(v.y)),
                                 fmaxf(fabsf(v.z), fabsf(v.w))));
    }
#pragma unroll
    for (int m = 1; m <= 8; m <<= 1) amax = fmaxf(amax, __shfl_xor(amax, m));
    if (l16 == 0) {
        float s = fmaxf(amax / 127.0f, 1e-8f);
        srow[r] = s;
        scale[row0g + r] = s;
    }
    __syncthreads();
    int total = (cols >> 4) * 16;
    size_t obase = (size_t)p * 32768;
    for (int idx = tid; idx < total; idx += 256) {
        int f = idx >> 6, q = (idx >> 4) & 3, rr = idx & 15;
        const float* src = in + (size_t)(lr0 + rr) * cols + f * 64 + q * 16;
        float s = srow[rr];
        unsigned int wds[4];
#pragma unroll
        for (int g = 0; g < 4; ++g) {
            float4 v = *(const float4*)(src + g * 4);
            int b0 = (int)fminf(fmaxf(rintf(v.x / s), -127.f), 127.f);
            int b1 = (int)fminf(fmaxf(rintf(v.y / s), -127.f), 127.f);
            int b2 = (int)fminf(fmaxf(rintf(v.z / s), -127.f), 127.f);
            int b3 = (int)fminf(fmaxf(rintf(v.w / s), -127.f), 127.f);
            wds[g] = (b0 & 255) | ((b1 & 255) << 8) | ((b2 & 255) << 16) | ((b3 & 255) << 24);
        }
        *(uint4*)(out + obase + (size_t)idx * 16) =
            make_uint4(wds[0], wds[1], wds[2], wds[3]);
    }
}

// ---------------- fused max-aware split-K combine + row quant (attn raw -> a_i8) ----------
__global__ __launch_bounds__(256) void row_quant_red_k(const float* __restrict__ attn2,
        const float* __restrict__ pp, const float* __restrict__ zb,
        signed char* __restrict__ out, float* __restrict__ scale) {
    int row0 = blockIdx.x * 16;
    int tid = threadIdx.x;
    __shared__ float srow[16];
    __shared__ float4 spvt[16][17];     // (w0, w1, spv, -)
    {
        int r = tid >> 4, h = tid & 15;
        int row = row0 + r;
        int t32 = row >> 6, rr = row & 63;
        const float2* zb2 = (const float2*)zb;
        float2 a0 = zb2[(((size_t)h * 32 + t32) * 2 + 0) * 64 + rr];
        float2 a1 = zb2[(((size_t)h * 32 + t32) * 2 + 1) * 64 + rr];
        float M = fmaxf(a0.x, a1.x);
        float w0 = __expf(a0.x - M), w1 = __expf(a1.x - M);
        float Zt = a0.y * w0 + a1.y * w1;
        float spv = fmaxf((1.0f / Zt) / 127.0f, 1e-8f);
        spvt[r][h] = make_float4(w0, w1, spv, 0.f);
    }
    __syncthreads();
    int r = tid >> 4, l16 = tid & 15;
    int row = row0 + r;
    const float4* x4 = (const float4*)(attn2 + (size_t)row * 2048);
    size_t ppr = ((size_t)(row >> 6) * 64 + (row & 63)) * 128;
    float amax = 0.f;
    for (int c4 = l16; c4 < 512; c4 += 16) {
        float4 v = x4[c4];
        int h = c4 >> 5;
        int j = (c4 & 31) * 4;
        float4 pv = *(const float4*)&pp[(size_t)h * 32 * 64 * 128 + ppr + j];
        float4 wz = spvt[r][h];
        v.x = (v.x * wz.x + pv.x * wz.y) * wz.z;
        v.y = (v.y * wz.x + pv.y * wz.y) * wz.z;
        v.z = (v.z * wz.x + pv.z * wz.y) * wz.z;
        v.w = (v.w * wz.x + pv.w * wz.y) * wz.z;
        amax = fmaxf(amax, fmaxf(fmaxf(fabsf(v.x), fabsf(v.y)),
                                 fmaxf(fabsf(v.z), fabsf(v.w))));
    }
#pragma unroll
    for (int m = 1; m <= 8; m <<= 1) amax = fmaxf(amax, __shfl_xor(amax, m));
    if (l16 == 0) {
        float s = fmaxf(amax / 127.0f, 1e-8f);
        srow[r] = s;
        scale[row0 + r] = s;
    }
    __syncthreads();
    size_t obase = ((size_t)(row0 >> 4) * 32) << 10;
    for (int idx = tid; idx < 2048; idx += 256) {
        int f = idx >> 6, q = (idx >> 4) & 3, rr16 = idx & 15;
        int rowb = row0 + rr16;
        int colb = f * 64 + q * 16;
        const float* src = attn2 + (size_t)rowb * 2048 + colb;
        float s = srow[rr16];
        int h = f >> 1;
        float4 wz = spvt[rr16][h];
        size_t ppb = (size_t)h * 32 * 64 * 128
                   + ((size_t)(rowb >> 6) * 64 + (rowb & 63)) * 128 + (colb & 127);
        unsigned int wds[4];
#pragma unroll
        for (int g = 0; g < 4; ++g) {
            float4 v = *(const float4*)(src + g * 4);
            float4 pv = *(const float4*)&pp[ppb + g * 4];
            v.x = (v.x * wz.x + pv.x * wz.y) * wz.z;
            v.y = (v.y * wz.x + pv.y * wz.y) * wz.z;
            v.z = (v.z * wz.x + pv.z * wz.y) * wz.z;
            v.w = (v.w * wz.x + pv.w * wz.y) * wz.z;
            int b0 = (int)fminf(fmaxf(rintf(v.x / s), -127.f), 127.f);
            int b1 = (int)fminf(fmaxf(rintf(v.y / s), -127.f), 127.f);
            int b2 = (int)fminf(fmaxf(rintf(v.z / s), -127.f), 127.f);
            int b3 = (int)fminf(fmaxf(rintf(v.w / s), -127.f), 127.f);
            wds[g] = (b0 & 255) | ((b1 & 255) << 8) | ((b2 & 255) << 16) | ((b3 & 255) << 24);
        }
        *(uint4*)(out + obase + (size_t)idx * 16) =
            make_uint4(wds[0], wds[1], wds[2], wds[3]);
    }
}

// ---------------- O-projection GEMM: 128x64 tile -> 512 blocks ----------------
__global__ __launch_bounds__(256, 3) void gemm_o_k(const signed char* __restrict__ A,
        const float* __restrict__ sa, const signed char* __restrict__ B,
        const float* __restrict__ sb, float* __restrict__ C, int M, int N, int K) {
    __shared__ __align__(16) signed char lsA[3][8192];
    __shared__ __align__(16) signed char lsB[3][4096];
    int tid = threadIdx.x;
    int w = tid >> 6, l = tid & 63;
    int wr = w >> 1, wc = w & 1;
    int lrow = l & 15;
    int m0 = blockIdx.y * 128, n0 = blockIdx.x * 64;
    int kb6 = K >> 6;
    v4i acc[4][2];
#pragma unroll
    for (int i = 0; i < 4; ++i)
#pragma unroll
        for (int j = 0; j < 2; ++j) acc[i][j] = (v4i){0, 0, 0, 0};

    auto stage = [&](int buf, int k6) {
#pragma unroll
        for (int a = 0; a < 2; ++a) {
            int f = a * 4 + w;
            ASYNC16(A + (((size_t)(((m0 >> 4) + f) * kb6 + k6)) << 10) + l * 16,
                    lsA[buf] + f * 1024);
        }
        ASYNC16(B + (((size_t)(((n0 >> 4) + w) * kb6 + k6)) << 10) + l * 16,
                lsB[buf] + w * 1024);
    };

    stage(0, 0);
    if (kb6 > 1) {
        stage(1, 1);
        asm volatile("s_waitcnt vmcnt(3)" ::: "memory");
    } else {
        asm volatile("s_waitcnt vmcnt(0)" ::: "memory");
    }
    __builtin_amdgcn_s_barrier();
    for (int t = 0; t < kb6; ++t) {
        if (t + 2 < kb6) stage((t + 2) % 3, t + 2);
        int cur = t % 3;
        v4i af[4], bf[2];
#pragma unroll
        for (int i = 0; i < 4; ++i) af[i] = *(const v4i*)(lsA[cur] + (wr * 4 + i) * 1024 + l * 16);
#pragma unroll
        for (int j = 0; j < 2; ++j) bf[j] = *(const v4i*)(lsB[cur] + (wc * 2 + j) * 1024 + l * 16);
#pragma unroll
        for (int i = 0; i < 4; ++i)
#pragma unroll
            for (int j = 0; j < 2; ++j)
                acc[i][j] = __builtin_amdgcn_mfma_i32_16x16x64_i8(af[i], bf[j], acc[i][j], 0, 0, 0);
        if (t + 2 < kb6) asm volatile("s_waitcnt vmcnt(3)" ::: "memory");
        else             asm volatile("s_waitcnt vmcnt(0)" ::: "memory");
        __builtin_amdgcn_s_barrier();
    }
    int r0 = m0 + wr * 64, c0 = n0 + wc * 32;
    int lg = l >> 4;
    float sbv[2];
#pragma unroll
    for (int j = 0; j < 2; ++j) sbv[j] = sb[c0 + j * 16 + lrow];
#pragma unroll
    for (int i = 0; i < 4; ++i) {
        float4 s4 = *(const float4*)(sa + r0 + i * 16 + lg * 4);
        float sav[4] = {s4.x, s4.y, s4.z, s4.w};
#pragma unroll
        for (int j = 0; j < 2; ++j) {
#pragma unroll
            for (int reg = 0; reg < 4; ++reg) {
                int rr = r0 + i * 16 + lg * 4 + reg;
                C[(size_t)rr * N + c0 + j * 16 + lrow] = (float)acc[i][j][reg] * (sav[reg] * sbv[j]);
            }
        }
    }
}

// ---------------- QKV GEMM with fused rmsnorm+rope+quant / V-transpose epilogue ----------
__global__ __launch_bounds__(256, 2) void gemm_qkv_k(const signed char* __restrict__ A,
        const float* __restrict__ sa, const signed char* __restrict__ B,
        const float* __restrict__ sb,
        const float* __restrict__ qw, const float* __restrict__ kw,
        const float* __restrict__ ct, const float* __restrict__ st,
        signed char* __restrict__ q_i8, float* __restrict__ sq,
        signed char* __restrict__ k_i8, float* __restrict__ sk,
        unsigned short* __restrict__ vtT) {
    __shared__ __align__(16) char smem[68608];
    signed char (*lsA)[8192] = (signed char(*)[8192])smem;
    signed char (*lsB)[8192] = (signed char(*)[8192])(smem + 24576);
    float (*tile)[132] = (float(*)[132])smem;
    float* srow = (float*)(smem + 67584);
    int tid = threadIdx.x;
    int w = tid >> 6, l = tid & 63;
    int wr = w >> 1, wc = w & 1;
    int lrow = l & 15, lg = l >> 4;
    int m0 = blockIdx.y * 128, n0 = blockIdx.x * 128;
    const int kb6 = 32;
    v4i acc[4][4];
#pragma unroll
    for (int i = 0; i < 4; ++i)
#pragma unroll
        for (int j = 0; j < 4; ++j) acc[i][j] = (v4i){0, 0, 0, 0};

    auto stage = [&](int buf, int k6) {
#pragma unroll
        for (int a = 0; a < 2; ++a) {
            int f = a * 4 + w;
            ASYNC16(A + (((size_t)(((m0 >> 4) + f) * kb6 + k6)) << 10) + l * 16,
                    lsA[buf] + f * 1024);
            ASYNC16(B + (((size_t)(((n0 >> 4) + f) * kb6 + k6)) << 10) + l * 16,
                    lsB[buf] + f * 1024);
        }
    };

    stage(0, 0);
    stage(1, 1);
    asm volatile("s_waitcnt vmcnt(4)" ::: "memory");
    __builtin_amdgcn_s_barrier();
    for (int t = 0; t < kb6; ++t) {
        if (t + 2 < kb6) stage((t + 2) % 3, t + 2);
        int cur = t % 3;
        v4i af[4], bf[4];
#pragma unroll
        for (int i = 0; i < 4; ++i) af[i] = *(const v4i*)(lsA[cur] + (wr * 4 + i) * 1024 + l * 16);
#pragma unroll
        for (int j = 0; j < 4; ++j) bf[j] = *(const v4i*)(lsB[cur] + (wc * 4 + j) * 1024 + l * 16);
#pragma unroll
        for (int i = 0; i < 4; ++i)
#pragma unroll
            for (int j = 0; j < 4; ++j)
                acc[i][j] = __builtin_amdgcn_mfma_i32_16x16x64_i8(af[i], bf[j], acc[i][j], 0, 0, 0);
        if (t + 2 < kb6) asm volatile("s_waitcnt vmcnt(4)" ::: "memory");
        else             asm volatile("s_waitcnt vmcnt(0)" ::: "memory");
        __builtin_amdgcn_s_barrier();
    }
    {
        int c0 = n0 + wc * 64;
        float sbv[4];
#pragma unroll
        for (int j = 0; j < 4; ++j) sbv[j] = sb[c0 + j * 16 + lrow];
#pragma unroll
        for (int i = 0; i < 4; ++i) {
            float4 s4 = *(const float4*)(sa + m0 + wr * 64 + i * 16 + lg * 4);
            float sav[4] = {s4.x, s4.y, s4.z, s4.w};
#pragma unroll
            for (int j = 0; j < 4; ++j)
#pragma unroll
                for (int reg = 0; reg < 4; ++reg)
                    tile[wr * 64 + i * 16 + lg * 4 + reg][wc * 64 + j * 16 + lrow] =
                        (float)acc[i][j][reg] * (sav[reg] * sbv[j]);
        }
    }
    __syncthreads();
    int slot = n0 >> 7;
    if (slot < 24) {
        const float* wn = (slot < 16) ? qw : kw;
        signed char* dst8 = (slot < 16) ? q_i8 + (size_t)slot * (SEQ * 128)
                                        : k_i8 + (size_t)(slot - 16) * (SEQ * 128);
        float* sdst = (slot < 16) ? sq + (size_t)slot * SEQ : sk + (size_t)(slot - 16) * SEQ;
        float wn0 = wn[l], wn1 = wn[l + 64];
        for (int it = 0; it < 32; ++it) {
            int tl = it * 4 + w;
            int t = m0 + tl;
            float x0 = tile[tl][l];
            float x1 = tile[tl][l + 64];
            float ss = x0 * x0 + x1 * x1;
#pragma unroll
            for (int m = 1; m <= 32; m <<= 1) ss += __shfl_xor(ss, m);
            float rs = 1.0f / sqrtf(ss / 128.0f + 1e-6f);
            x0 = (x0 * rs) * wn0;
            x1 = (x1 * rs) * wn1;
            float cth = ct[t * 64 + l];
            float sth = st[t * 64 + l];
            float nx0 = x0 * cth - x1 * sth;
            float nx1 = x1 * cth + x0 * sth;
            float amax = fmaxf(fabsf(nx0), fabsf(nx1));
#pragma unroll
            for (int m = 1; m <= 32; m <<= 1) amax = fmaxf(amax, __shfl_xor(amax, m));
            float s = fmaxf(amax / 127.0f, 1e-8f);
            float q0 = fminf(fmaxf(rintf(nx0 / s), -127.f), 127.f);
            float q1 = fminf(fmaxf(rintf(nx1 / s), -127.f), 127.f);
            size_t ta0 = (size_t)(((t >> 4) * 2) << 10)
                       + (size_t)((((l >> 4) & 3) << 8) + ((t & 15) << 4) + (l & 15));
            dst8[ta0] = (signed char)(int)q0;
            dst8[ta0 + 1024] = (signed char)(int)q1;
            if (l == 0) sdst[t] = s;
        }
    } else {
        int kv = slot - 24;
        for (int it = 0; it < 32; ++it) {
            int tl = it * 4 + w;
            float x0 = tile[tl][l];
            float x1 = tile[tl][l + 64];
            float amax = fmaxf(fabsf(x0), fabsf(x1));
#pragma unroll
            for (int m = 1; m <= 32; m <<= 1) amax = fmaxf(amax, __shfl_xor(amax, m));
            if (l == 0) srow[tl] = fmaxf(amax / 127.0f, 1e-8f);
        }
        __syncthreads();
        int d = tid >> 1, th = (tid & 1) * 32;
        size_t base = (size_t)kv * (SEQ * 128);
#pragma unroll
        for (int kbl = 0; kbl < 2; ++kbl) {
            int kb = (m0 >> 6) + kbl;
#pragma unroll
            for (int j = 0; j < 32; j += 2) {
                int t64 = th + j;
                int tg = kbl * 64 + t64;
                float s0 = srow[tg], s1 = srow[tg + 1];
                float a = fminf(fmaxf(rintf(tile[tg][d] / s0), -127.f), 127.f) * s0;
                float b = fminf(fmaxf(rintf(tile[tg + 1][d] / s1), -127.f), 127.f) * s1;
                unsigned int ua = f2h_bits(a), ub = f2h_bits(b);
                int off = kb * 8192 + ((d >> 4) * 2 + ((t64 >> 5) & 1)) * 512
                        + (((d & 15) + (((t64 >> 3) & 3) << 4)) << 3) + (t64 & 7);
                *(unsigned int*)(vtT + base + off) = ua | (ub << 16);
            }
        }
    }
}

// ---------------- attention: online-softmax flash, 32-row sub-tiles -> 1024 blocks ----------
// Wave w: head hp*2+(w>>1), rows (w&1)*16..+16 of the 32-row sub-tile. K/V LDS shared by
// all 4 waves. V 2-deep, K single-buffer mid-iter refill. Raw accs + (m,Z); combine later.
__global__ __launch_bounds__(256, 2) void attn_k(const signed char* __restrict__ q_i8,
        const float* __restrict__ sq, const signed char* __restrict__ k_i8,
        const float* __restrict__ sk, const unsigned short* __restrict__ vtT,
        float* __restrict__ attn2, float* __restrict__ pp, float* __restrict__ zb) {
    __shared__ __align__(16) unsigned short vlds[2][8192];  // 32 KB
    __shared__ __align__(16) signed char klds[8192];        // 8 KB
    __shared__ __align__(16) unsigned short plds[4096];     // 8 KB wave-private
    int bx = blockIdx.x, hp = blockIdx.y;
    int qs = 63 - (bx >> 1), c = bx & 1;
    int qb = qs >> 1;                    // 64-row tile index (for pp/zb indexing)
    int q0s = qs * 32;
    int hsp = (qb + 2) >> 1;
    int kb0 = c ? hsp : 0;
    int kb1 = c ? (qb + 1) : hsp;
    int tid = threadIdx.x, w = tid >> 6, l = tid & 63;
    int lrow = l & 15, lg = l >> 4;
    int hh = hp * 2 + (w >> 1);          // this wave's head
    int wrow = (w & 1) * 16;             // row offset within the 32-row sub-tile
    int rrb = (qs & 1) * 32 + wrow;      // row offset within the 64-row tile

    if (kb0 >= kb1) {                    // qb==0 (qs 0,1), c==1: sentinel
        if (lrow == 0) {
            float2* zb2 = (float2*)zb;
            size_t z = (((size_t)hh * 32 + qb) * 2 + c) * 64;
#pragma unroll
            for (int reg = 0; reg < 4; ++reg)
                zb2[z + rrb + lg * 4 + reg] = make_float2(-1e30f, 0.f);
        }
        return;
    }

    const signed char* qt = q_i8 + (size_t)hh * (SEQ * 128)
                          + ((size_t)((qs * 2 + (w & 1)) * 2) << 10) + l * 16;
    v4i qf0 = *(const v4i*)(qt), qf1 = *(const v4i*)(qt + 1024);
    float4 s4 = *(const float4*)(sq + (size_t)hh * SEQ + q0s + wrow + lg * 4);
    float sqr[4] = {s4.x, s4.y, s4.z, s4.w};

    const signed char* kbase = k_i8 + (size_t)hp * (SEQ * 128);
    const float* skb = sk + (size_t)hp * SEQ;
    const unsigned short* vt = vtT + (size_t)hp * (SEQ * 128);

    auto issueV = [&](int kb) {     // 4 ASYNC16 / wave into vlds[kb&1]
        unsigned short* vb = &vlds[kb & 1][0];
#pragma unroll
        for (int a = 0; a < 4; ++a) {
            int fv = a * 4 + w;
            ASYNC16(vt + (size_t)kb * 8192 + fv * 512 + l * 8, vb + fv * 512);
        }
    };
    auto issueK = [&](int kb) {     // 2 ASYNC16 / wave into klds
#pragma unroll
        for (int a = 0; a < 2; ++a) {
            int f = a * 4 + w;
            ASYNC16(kbase + ((size_t)(kb * 8 + f) << 10) + l * 16, klds + f * 1024);
        }
    };

    v4f acc[8];
#pragma unroll
    for (int jd = 0; jd < 8; ++jd) acc[jd] = (v4f){0.f, 0.f, 0.f, 0.f};
    float zt[4] = {0.f, 0.f, 0.f, 0.f};
    float mr[4];
#pragma unroll
    for (int r = 0; r < 4; ++r) mr[r] = -1e30f;

    issueK(kb0);
    issueV(kb0);
    asm volatile("s_waitcnt vmcnt(0)" ::: "memory");
    __builtin_amdgcn_s_barrier();

    for (int kb = kb0; kb < kb1; ++kb) {
        int k0 = kb * 64;
        if (kb + 1 < kb1) issueV(kb + 1);
        v4i ka[8];
#pragma unroll
        for (int f = 0; f < 8; ++f)
            ka[f] = *(const v4i*)(klds + f * 1024 + l * 16);
        float skc[4];
#pragma unroll
        for (int j = 0; j < 4; ++j) skc[j] = skb[k0 + j * 16 + lrow];
        v4i sci[4];
#pragma unroll
        for (int j = 0; j < 4; ++j) {
            v4i z = {0, 0, 0, 0};
            v4i t0 = __builtin_amdgcn_mfma_i32_16x16x64_i8(qf0, ka[j * 2], z, 0, 0, 0);
            sci[j] = __builtin_amdgcn_mfma_i32_16x16x64_i8(qf1, ka[j * 2 + 1], t0, 0, 0, 0);
        }
        // all waves' klds reads complete (MFMA forced lgkm wait) -> safe to refill
        __builtin_amdgcn_s_barrier();
        if (kb + 1 < kb1) issueK(kb + 1);       // overlaps softmax + PV below
        float sv[4][4];
        float tm[4];
#pragma unroll
        for (int reg = 0; reg < 4; ++reg) tm[reg] = -1e30f;
#pragma unroll
        for (int reg = 0; reg < 4; ++reg) {
            int r = q0s + wrow + lg * 4 + reg;
#pragma unroll
            for (int j = 0; j < 4; ++j) {
                int cc = j * 16 + lrow;
                bool ok = (k0 + cc <= r);
                float ss = skc[j] * SM_SCALE;
                sv[reg][j] = ok ? ((float)sci[j][reg] * sqr[reg]) * ss : -1e30f;
                tm[reg] = fmaxf(tm[reg], sv[reg][j]);
            }
        }
#pragma unroll
        for (int reg = 0; reg < 4; ++reg) {
#pragma unroll
            for (int mask = 1; mask <= 8; mask <<= 1)
                tm[reg] = fmaxf(tm[reg], __shfl_xor(tm[reg], mask));
        }
        float ef[4];
#pragma unroll
        for (int reg = 0; reg < 4; ++reg) {
            float mn = fmaxf(mr[reg], tm[reg]);
            ef[reg] = __expf(mr[reg] - mn);
            mr[reg] = mn;
            zt[reg] *= ef[reg];
        }
        v4f efv = {ef[0], ef[1], ef[2], ef[3]};
#pragma unroll
        for (int jd = 0; jd < 8; ++jd) acc[jd] *= efv;
#pragma unroll
        for (int reg = 0; reg < 4; ++reg) {
            int rq = lg * 4 + reg;
#pragma unroll
            for (int j = 0; j < 4; ++j) {
                int cc = j * 16 + lrow;
                float pd = 0.f;
                float s = sv[reg][j];
                if (s > -5e29f) {
                    float e = __expf(s - mr[reg]);
                    zt[reg] += e;
                    pd = fminf(rintf(127.0f * e), 127.f);
                }
                plds[(w * 2 + (cc >> 5)) * 512 + (rq + 16 * ((cc >> 3) & 3)) * 8 + (cc & 7)] =
                    f2h_bits(pd);
            }
        }
        v8h pf0 = *(const v8h*)(plds + (w * 2 + 0) * 512 + l * 8);
        v8h pf1 = *(const v8h*)(plds + (w * 2 + 1) * 512 + l * 8);
        const unsigned short* vb = &vlds[kb & 1][0];
#pragma unroll
        for (int jd = 0; jd < 8; ++jd) {
            v8h vh0 = *(const v8h*)(vb + (jd * 2 + 0) * 512 + l * 8);
            v8h vh1 = *(const v8h*)(vb + (jd * 2 + 1) * 512 + l * 8);
            v4f t = acc[jd];
            t = __builtin_amdgcn_mfma_f32_16x16x32_f16(pf0, vh0, t, 0, 0, 0);
            t = __builtin_amdgcn_mfma_f32_16x16x32_f16(pf1, vh1, t, 0, 0, 0);
            acc[jd] = t;
        }
        // V(kb+1) + K(kb+1) were issued >=1 compute-phase ago: mostly-free wait
        asm volatile("s_waitcnt vmcnt(0)" ::: "memory");
        __builtin_amdgcn_s_barrier();
    }
#pragma unroll
    for (int reg = 0; reg < 4; ++reg) {
#pragma unroll
        for (int mask = 1; mask <= 8; mask <<= 1)
            zt[reg] += __shfl_xor(zt[reg], mask);
    }
    if (c == 0) {
#pragma unroll
        for (int jd = 0; jd < 8; ++jd)
#pragma unroll
            for (int reg = 0; reg < 4; ++reg) {
                int r = q0s + wrow + lg * 4 + reg;
                attn2[(size_t)r * DMODEL + hh * HDIM + jd * 16 + lrow] = acc[jd][reg];
            }
    } else {
#pragma unroll
        for (int jd = 0; jd < 8; ++jd)
#pragma unroll
            for (int reg = 0; reg < 4; ++reg) {
                int rr = rrb + lg * 4 + reg;
                pp[(((size_t)hh * 32 + qb) * 64 + rr) * 128 + jd * 16 + lrow] = acc[jd][reg];
            }
    }
    if (lrow == 0) {
        float2* zb2 = (float2*)zb;
        size_t z = (((size_t)hh * 32 + qb) * 2 + c) * 64;
#pragma unroll
        for (int reg = 0; reg < 4; ++reg)
            zb2[z + rrb + lg * 4 + reg] = make_float2(mr[reg], zt[reg]);
    }
}

extern "C" void kernel_launch(void* const* d_in, const int* in_sizes, int n_in,
                              void* d_out, int out_size, void* d_ws, size_t ws_size,
                              hipStream_t stream) {
    (void)in_sizes; (void)n_in; (void)out_size; (void)ws_size;
    const float* hidden = (const float*)d_in[0];
    const float* Wq = (const float*)d_in[1];
    const float* Wk = (const float*)d_in[2];
    const float* Wv = (const float*)d_in[3];
    const float* Wo = (const float*)d_in[4];
    const float* qw = (const float*)d_in[5];
    const float* kw = (const float*)d_in[6];
    const int* pos = (const int*)d_in[7];
    float* out = (float*)d_out;
    char* ws = (char*)d_ws;

    const size_t MB = 1024 * 1024;
    signed char* x_i8  = (signed char*)(ws);            // 16 MB tiled i8 block (x,wq,wk,wv,wo)
    signed char* wq_i8 = (signed char*)(ws + 4 * MB);
    signed char* wo_i8 = (signed char*)(ws + 12 * MB);
    signed char* q_i8  = (signed char*)(ws + 16 * MB);  // 4 MB (attn-tiled)
    signed char* k_i8  = (signed char*)(ws + 20 * MB);  // 2 MB (attn-tiled)
    float* sx  = (float*)(ws + 22 * MB);                // scales
    float* swq = sx + 2048;
    float* swo = sx + 6144;
    float* sq  = sx + 8192;                             // 16*2048
    float* sk  = sq + NH * SEQ;                         // 8*2048
    float* sa  = sk + NKV * SEQ;                        // 2048
    float* ct  = (float*)(ws + 22 * MB + 512 * 1024);   // 512 KB
    float* st  = (float*)(ws + 22 * MB + 1024 * 1024);  // 512 KB
    unsigned short* vtT = (unsigned short*)(ws + 24 * MB); // 4 MB
    float* zb    = (float*)(ws + 28 * MB);              // 512 KB (float2 m,Z per row/chunk)
    float* attn2 = (float*)(ws + 30 * MB);              // 16 MB (chunk-0 raw accs)
    float* pp    = (float*)(ws + 46 * MB);              // 16 MB (chunk-1 raw accs)
    signed char* a_i8 = x_i8;

    quant_rope_k<<<1024, 256, 0, stream>>>(hidden, Wq, Wk, Wv, Wo, pos, x_i8, sx, ct, st);

    gemm_qkv_k<<<dim3(32, 16), 256, 0, stream>>>(x_i8, sx, wq_i8, swq, qw, kw, ct, st,
                                                 q_i8, sq, k_i8, sk, vtT);

    attn_k<<<dim3(128, 8), 256, 0, stream>>>(q_i8, sq, k_i8, sk, vtT, attn2, pp, zb);

    row_quant_red_k<<<128, 256, 0, stream>>>(attn2, pp, zb, a_i8, sa);
    gemm_o_k<<<dim3(32, 16), 256, 0, stream>>>(a_i8, sa, wo_i8, swo, out, 2048, 2048, 2048);
}

// Round 21
// 165.232 us; speedup vs baseline: 1.0483x; 1.0311x over previous
//
#include <hip/hip_runtime.h>
#include <math.h>

#define NH 16
#define NKV 8
#define HDIM 128
#define SEQ 2048
#define DMODEL 2048

typedef int   v4i __attribute__((ext_vector_type(4)));
typedef float v4f __attribute__((ext_vector_type(4)));
typedef _Float16 v8h __attribute__((ext_vector_type(8)));

static constexpr float SM_SCALE = 0.08838834764831843f; // 128**-0.5

#define GLOBP(p) (__attribute__((address_space(1))) void*)(p)
#define LDSP(p)  (__attribute__((address_space(3))) void*)(p)
#define ASYNC16(g, l) __builtin_amdgcn_global_load_lds(GLOBP(g), LDSP(l), 16, 0, 0)

// Fragment-tiled i8 layout for X[R][K] (R%16==0, K%64==0):
// frag (r>>4, k>>6) is 1024B; within: byte = ((k>>4)&3)*256 + (r&15)*16 + (k&15).

__device__ __forceinline__ unsigned short f2h_bits(float x) {
    _Float16 h = (_Float16)x;               // RN, exact for small ints
    return __builtin_bit_cast(unsigned short, h);
}

// ---------------- merged per-row int8 quant (5 inputs) + rope table ----------------
__global__ __launch_bounds__(256) void quant_rope_k(const float* __restrict__ hidden,
        const float* __restrict__ Wq, const float* __restrict__ Wk,
        const float* __restrict__ Wv, const float* __restrict__ Wo,
        const int* __restrict__ pos_ids,
        signed char* __restrict__ out, float* __restrict__ scale,
        float* __restrict__ ct, float* __restrict__ st) {
    int p = blockIdx.x;
    if (p >= 512) {
        int t = (p - 512) * 4 + (threadIdx.x >> 6);
        int fi = threadIdx.x & 63;
        float inv = 1.0f / (float)pow(1.0e6, (double)fi / 64.0);
        float fr = (float)pos_ids[t] * inv;
        float sn, c;
        sincosf(fr, &sn, &c);
        ct[t * 64 + fi] = c;
        st[t * 64 + fi] = sn;
        return;
    }
    int row0g = p * 16;
    const float* in; int lr0;
    if (row0g < 2048)      { in = hidden; lr0 = row0g; }
    else if (row0g < 4096) { in = Wq; lr0 = row0g - 2048; }
    else if (row0g < 5120) { in = Wk; lr0 = row0g - 4096; }
    else if (row0g < 6144) { in = Wv; lr0 = row0g - 5120; }
    else                   { in = Wo; lr0 = row0g - 6144; }
    const int cols = 2048;
    int tid = threadIdx.x;
    __shared__ float srow[16];
    int r = tid >> 4, l16 = tid & 15;
    const float4* x4 = (const float4*)(in + (size_t)(lr0 + r) * cols);
    float amax = 0.f;
    for (int c4 = l16; c4 < (cols >> 2); c4 += 16) {
        float4 v = x4[c4];
        amax = fmaxf(amax, fmaxf(fmaxf(fabsf(v.x), fabsf(v.y)),
                                 fmaxf(fabsf(v.z), fabsf(v.w))));
    }
#pragma unroll
    for (int m = 1; m <= 8; m <<= 1) amax = fmaxf(amax, __shfl_xor(amax, m));
    if (l16 == 0) {
        float s = fmaxf(amax / 127.0f, 1e-8f);
        srow[r] = s;
        scale[row0g + r] = s;
    }
    __syncthreads();
    int total = (cols >> 4) * 16;
    size_t obase = (size_t)p * 32768;
    for (int idx = tid; idx < total; idx += 256) {
        int f = idx >> 6, q = (idx >> 4) & 3, rr = idx & 15;
        const float* src = in + (size_t)(lr0 + rr) * cols + f * 64 + q * 16;
        float s = srow[rr];
        unsigned int wds[4];
#pragma unroll
        for (int g = 0; g < 4; ++g) {
            float4 v = *(const float4*)(src + g * 4);
            int b0 = (int)fminf(fmaxf(rintf(v.x / s), -127.f), 127.f);
            int b1 = (int)fminf(fmaxf(rintf(v.y / s), -127.f), 127.f);
            int b2 = (int)fminf(fmaxf(rintf(v.z / s), -127.f), 127.f);
            int b3 = (int)fminf(fmaxf(rintf(v.w / s), -127.f), 127.f);
            wds[g] = (b0 & 255) | ((b1 & 255) << 8) | ((b2 & 255) << 16) | ((b3 & 255) << 24);
        }
        *(uint4*)(out + obase + (size_t)idx * 16) =
            make_uint4(wds[0], wds[1], wds[2], wds[3]);
    }
}

// ---------------- fused max-aware split-K combine + row quant (attn raw -> a_i8) ----------
__global__ __launch_bounds__(256) void row_quant_red_k(const float* __restrict__ attn2,
        const float* __restrict__ pp, const float* __restrict__ zb,
        signed char* __restrict__ out, float* __restrict__ scale) {
    int row0 = blockIdx.x * 16;
    int tid = threadIdx.x;
    __shared__ float srow[16];
    __shared__ float4 spvt[16][17];     // (w0, w1, spv, -)
    {
        int r = tid >> 4, h = tid & 15;
        int row = row0 + r;
        int t32 = row >> 6, rr = row & 63;
        const float2* zb2 = (const float2*)zb;
        float2 a0 = zb2[(((size_t)h * 32 + t32) * 2 + 0) * 64 + rr];
        float2 a1 = zb2[(((size_t)h * 32 + t32) * 2 + 1) * 64 + rr];
        float M = fmaxf(a0.x, a1.x);
        float w0 = __expf(a0.x - M), w1 = __expf(a1.x - M);
        float Zt = a0.y * w0 + a1.y * w1;
        float spv = fmaxf((1.0f / Zt) / 127.0f, 1e-8f);
        spvt[r][h] = make_float4(w0, w1, spv, 0.f);
    }
    __syncthreads();
    int r = tid >> 4, l16 = tid & 15;
    int row = row0 + r;
    const float4* x4 = (const float4*)(attn2 + (size_t)row * 2048);
    size_t ppr = ((size_t)(row >> 6) * 64 + (row & 63)) * 128;
    float amax = 0.f;
    for (int c4 = l16; c4 < 512; c4 += 16) {
        float4 v = x4[c4];
        int h = c4 >> 5;
        int j = (c4 & 31) * 4;
        float4 pv = *(const float4*)&pp[(size_t)h * 32 * 64 * 128 + ppr + j];
        float4 wz = spvt[r][h];
        v.x = (v.x * wz.x + pv.x * wz.y) * wz.z;
        v.y = (v.y * wz.x + pv.y * wz.y) * wz.z;
        v.z = (v.z * wz.x + pv.z * wz.y) * wz.z;
        v.w = (v.w * wz.x + pv.w * wz.y) * wz.z;
        amax = fmaxf(amax, fmaxf(fmaxf(fabsf(v.x), fabsf(v.y)),
                                 fmaxf(fabsf(v.z), fabsf(v.w))));
    }
#pragma unroll
    for (int m = 1; m <= 8; m <<= 1) amax = fmaxf(amax, __shfl_xor(amax, m));
    if (l16 == 0) {
        float s = fmaxf(amax / 127.0f, 1e-8f);
        srow[r] = s;
        scale[row0 + r] = s;
    }
    __syncthreads();
    size_t obase = ((size_t)(row0 >> 4) * 32) << 10;
    for (int idx = tid; idx < 2048; idx += 256) {
        int f = idx >> 6, q = (idx >> 4) & 3, rr16 = idx & 15;
        int rowb = row0 + rr16;
        int colb = f * 64 + q * 16;
        const float* src = attn2 + (size_t)rowb * 2048 + colb;
        float s = srow[rr16];
        int h = f >> 1;
        float4 wz = spvt[rr16][h];
        size_t ppb = (size_t)h * 32 * 64 * 128
                   + ((size_t)(rowb >> 6) * 64 + (rowb & 63)) * 128 + (colb & 127);
        unsigned int wds[4];
#pragma unroll
        for (int g = 0; g < 4; ++g) {
            float4 v = *(const float4*)(src + g * 4);
            float4 pv = *(const float4*)&pp[ppb + g * 4];
            v.x = (v.x * wz.x + pv.x * wz.y) * wz.z;
            v.y = (v.y * wz.x + pv.y * wz.y) * wz.z;
            v.z = (v.z * wz.x + pv.z * wz.y) * wz.z;
            v.w = (v.w * wz.x + pv.w * wz.y) * wz.z;
            int b0 = (int)fminf(fmaxf(rintf(v.x / s), -127.f), 127.f);
            int b1 = (int)fminf(fmaxf(rintf(v.y / s), -127.f), 127.f);
            int b2 = (int)fminf(fmaxf(rintf(v.z / s), -127.f), 127.f);
            int b3 = (int)fminf(fmaxf(rintf(v.w / s), -127.f), 127.f);
            wds[g] = (b0 & 255) | ((b1 & 255) << 8) | ((b2 & 255) << 16) | ((b3 & 255) << 24);
        }
        *(uint4*)(out + obase + (size_t)idx * 16) =
            make_uint4(wds[0], wds[1], wds[2], wds[3]);
    }
}

// ---------------- O-projection GEMM: 128x64 tile -> 512 blocks ----------------
__global__ __launch_bounds__(256, 3) void gemm_o_k(const signed char* __restrict__ A,
        const float* __restrict__ sa, const signed char* __restrict__ B,
        const float* __restrict__ sb, float* __restrict__ C, int M, int N, int K) {
    __shared__ __align__(16) signed char lsA[3][8192];
    __shared__ __align__(16) signed char lsB[3][4096];
    int tid = threadIdx.x;
    int w = tid >> 6, l = tid & 63;
    int wr = w >> 1, wc = w & 1;
    int lrow = l & 15;
    int m0 = blockIdx.y * 128, n0 = blockIdx.x * 64;
    int kb6 = K >> 6;
    v4i acc[4][2];
#pragma unroll
    for (int i = 0; i < 4; ++i)
#pragma unroll
        for (int j = 0; j < 2; ++j) acc[i][j] = (v4i){0, 0, 0, 0};

    auto stage = [&](int buf, int k6) {
#pragma unroll
        for (int a = 0; a < 2; ++a) {
            int f = a * 4 + w;
            ASYNC16(A + (((size_t)(((m0 >> 4) + f) * kb6 + k6)) << 10) + l * 16,
                    lsA[buf] + f * 1024);
        }
        ASYNC16(B + (((size_t)(((n0 >> 4) + w) * kb6 + k6)) << 10) + l * 16,
                lsB[buf] + w * 1024);
    };

    stage(0, 0);
    if (kb6 > 1) {
        stage(1, 1);
        asm volatile("s_waitcnt vmcnt(3)" ::: "memory");
    } else {
        asm volatile("s_waitcnt vmcnt(0)" ::: "memory");
    }
    __builtin_amdgcn_s_barrier();
    for (int t = 0; t < kb6; ++t) {
        if (t + 2 < kb6) stage((t + 2) % 3, t + 2);
        int cur = t % 3;
        v4i af[4], bf[2];
#pragma unroll
        for (int i = 0; i < 4; ++i) af[i] = *(const v4i*)(lsA[cur] + (wr * 4 + i) * 1024 + l * 16);
#pragma unroll
        for (int j = 0; j < 2; ++j) bf[j] = *(const v4i*)(lsB[cur] + (wc * 2 + j) * 1024 + l * 16);
#pragma unroll
        for (int i = 0; i < 4; ++i)
#pragma unroll
            for (int j = 0; j < 2; ++j)
                acc[i][j] = __builtin_amdgcn_mfma_i32_16x16x64_i8(af[i], bf[j], acc[i][j], 0, 0, 0);
        if (t + 2 < kb6) asm volatile("s_waitcnt vmcnt(3)" ::: "memory");
        else             asm volatile("s_waitcnt vmcnt(0)" ::: "memory");
        __builtin_amdgcn_s_barrier();
    }
    int r0 = m0 + wr * 64, c0 = n0 + wc * 32;
    int lg = l >> 4;
    float sbv[2];
#pragma unroll
    for (int j = 0; j < 2; ++j) sbv[j] = sb[c0 + j * 16 + lrow];
#pragma unroll
    for (int i = 0; i < 4; ++i) {
        float4 s4 = *(const float4*)(sa + r0 + i * 16 + lg * 4);
        float sav[4] = {s4.x, s4.y, s4.z, s4.w};
#pragma unroll
        for (int j = 0; j < 2; ++j) {
#pragma unroll
            for (int reg = 0; reg < 4; ++reg) {
                int rr = r0 + i * 16 + lg * 4 + reg;
                C[(size_t)rr * N + c0 + j * 16 + lrow] = (float)acc[i][j][reg] * (sav[reg] * sbv[j]);
            }
        }
    }
}

// ---------------- QKV GEMM with fused rmsnorm+rope+quant / V-transpose epilogue ----------
__global__ __launch_bounds__(256, 2) void gemm_qkv_k(const signed char* __restrict__ A,
        const float* __restrict__ sa, const signed char* __restrict__ B,
        const float* __restrict__ sb,
        const float* __restrict__ qw, const float* __restrict__ kw,
        const float* __restrict__ ct, const float* __restrict__ st,
        signed char* __restrict__ q_i8, float* __restrict__ sq,
        signed char* __restrict__ k_i8, float* __restrict__ sk,
        unsigned short* __restrict__ vtT) {
    __shared__ __align__(16) char smem[68608];
    signed char (*lsA)[8192] = (signed char(*)[8192])smem;
    signed char (*lsB)[8192] = (signed char(*)[8192])(smem + 24576);
    float (*tile)[132] = (float(*)[132])smem;
    float* srow = (float*)(smem + 67584);
    int tid = threadIdx.x;
    int w = tid >> 6, l = tid & 63;
    int wr = w >> 1, wc = w & 1;
    int lrow = l & 15, lg = l >> 4;
    int m0 = blockIdx.y * 128, n0 = blockIdx.x * 128;
    const int kb6 = 32;
    v4i acc[4][4];
#pragma unroll
    for (int i = 0; i < 4; ++i)
#pragma unroll
        for (int j = 0; j < 4; ++j) acc[i][j] = (v4i){0, 0, 0, 0};

    auto stage = [&](int buf, int k6) {
#pragma unroll
        for (int a = 0; a < 2; ++a) {
            int f = a * 4 + w;
            ASYNC16(A + (((size_t)(((m0 >> 4) + f) * kb6 + k6)) << 10) + l * 16,
                    lsA[buf] + f * 1024);
            ASYNC16(B + (((size_t)(((n0 >> 4) + f) * kb6 + k6)) << 10) + l * 16,
                    lsB[buf] + f * 1024);
        }
    };

    stage(0, 0);
    stage(1, 1);
    asm volatile("s_waitcnt vmcnt(4)" ::: "memory");
    __builtin_amdgcn_s_barrier();
    for (int t = 0; t < kb6; ++t) {
        if (t + 2 < kb6) stage((t + 2) % 3, t + 2);
        int cur = t % 3;
        v4i af[4], bf[4];
#pragma unroll
        for (int i = 0; i < 4; ++i) af[i] = *(const v4i*)(lsA[cur] + (wr * 4 + i) * 1024 + l * 16);
#pragma unroll
        for (int j = 0; j < 4; ++j) bf[j] = *(const v4i*)(lsB[cur] + (wc * 4 + j) * 1024 + l * 16);
#pragma unroll
        for (int i = 0; i < 4; ++i)
#pragma unroll
            for (int j = 0; j < 4; ++j)
                acc[i][j] = __builtin_amdgcn_mfma_i32_16x16x64_i8(af[i], bf[j], acc[i][j], 0, 0, 0);
        if (t + 2 < kb6) asm volatile("s_waitcnt vmcnt(4)" ::: "memory");
        else             asm volatile("s_waitcnt vmcnt(0)" ::: "memory");
        __builtin_amdgcn_s_barrier();
    }
    {
        int c0 = n0 + wc * 64;
        float sbv[4];
#pragma unroll
        for (int j = 0; j < 4; ++j) sbv[j] = sb[c0 + j * 16 + lrow];
#pragma unroll
        for (int i = 0; i < 4; ++i) {
            float4 s4 = *(const float4*)(sa + m0 + wr * 64 + i * 16 + lg * 4);
            float sav[4] = {s4.x, s4.y, s4.z, s4.w};
#pragma unroll
            for (int j = 0; j < 4; ++j)
#pragma unroll
                for (int reg = 0; reg < 4; ++reg)
                    tile[wr * 64 + i * 16 + lg * 4 + reg][wc * 64 + j * 16 + lrow] =
                        (float)acc[i][j][reg] * (sav[reg] * sbv[j]);
        }
    }
    __syncthreads();
    int slot = n0 >> 7;
    if (slot < 24) {
        const float* wn = (slot < 16) ? qw : kw;
        signed char* dst8 = (slot < 16) ? q_i8 + (size_t)slot * (SEQ * 128)
                                        : k_i8 + (size_t)(slot - 16) * (SEQ * 128);
        float* sdst = (slot < 16) ? sq + (size_t)slot * SEQ : sk + (size_t)(slot - 16) * SEQ;
        float wn0 = wn[l], wn1 = wn[l + 64];
        for (int it = 0; it < 32; ++it) {
            int tl = it * 4 + w;
            int t = m0 + tl;
            float x0 = tile[tl][l];
            float x1 = tile[tl][l + 64];
            float ss = x0 * x0 + x1 * x1;
#pragma unroll
            for (int m = 1; m <= 32; m <<= 1) ss += __shfl_xor(ss, m);
            float rs = 1.0f / sqrtf(ss / 128.0f + 1e-6f);
            x0 = (x0 * rs) * wn0;
            x1 = (x1 * rs) * wn1;
            float cth = ct[t * 64 + l];
            float sth = st[t * 64 + l];
            float nx0 = x0 * cth - x1 * sth;
            float nx1 = x1 * cth + x0 * sth;
            float amax = fmaxf(fabsf(nx0), fabsf(nx1));
#pragma unroll
            for (int m = 1; m <= 32; m <<= 1) amax = fmaxf(amax, __shfl_xor(amax, m));
            float s = fmaxf(amax / 127.0f, 1e-8f);
            float q0 = fminf(fmaxf(rintf(nx0 / s), -127.f), 127.f);
            float q1 = fminf(fmaxf(rintf(nx1 / s), -127.f), 127.f);
            size_t ta0 = (size_t)(((t >> 4) * 2) << 10)
                       + (size_t)((((l >> 4) & 3) << 8) + ((t & 15) << 4) + (l & 15));
            dst8[ta0] = (signed char)(int)q0;
            dst8[ta0 + 1024] = (signed char)(int)q1;
            if (l == 0) sdst[t] = s;
        }
    } else {
        int kv = slot - 24;
        for (int it = 0; it < 32; ++it) {
            int tl = it * 4 + w;
            float x0 = tile[tl][l];
            float x1 = tile[tl][l + 64];
            float amax = fmaxf(fabsf(x0), fabsf(x1));
#pragma unroll
            for (int m = 1; m <= 32; m <<= 1) amax = fmaxf(amax, __shfl_xor(amax, m));
            if (l == 0) srow[tl] = fmaxf(amax / 127.0f, 1e-8f);
        }
        __syncthreads();
        int d = tid >> 1, th = (tid & 1) * 32;
        size_t base = (size_t)kv * (SEQ * 128);
#pragma unroll
        for (int kbl = 0; kbl < 2; ++kbl) {
            int kb = (m0 >> 6) + kbl;
#pragma unroll
            for (int j = 0; j < 32; j += 2) {
                int t64 = th + j;
                int tg = kbl * 64 + t64;
                float s0 = srow[tg], s1 = srow[tg + 1];
                float a = fminf(fmaxf(rintf(tile[tg][d] / s0), -127.f), 127.f) * s0;
                float b = fminf(fmaxf(rintf(tile[tg + 1][d] / s1), -127.f), 127.f) * s1;
                unsigned int ua = f2h_bits(a), ub = f2h_bits(b);
                int off = kb * 8192 + ((d >> 4) * 2 + ((t64 >> 5) & 1)) * 512
                        + (((d & 15) + (((t64 >> 3) & 3) << 4)) << 3) + (t64 & 7);
                *(unsigned int*)(vtT + base + off) = ua | (ub << 16);
            }
        }
    }
}

// ---------------- attention: online-softmax flash, 32-row sub-tiles -> 1024 blocks ----------
// Wave w: head hp*2+(w>>1), rows (w&1)*16..+16. Unmasked-tile fast path (wave-uniform
// branch) + s_setprio around MFMA clusters. Raw accs + (m,Z); combine in row_quant_red.
__global__ __launch_bounds__(256, 2) void attn_k(const signed char* __restrict__ q_i8,
        const float* __restrict__ sq, const signed char* __restrict__ k_i8,
        const float* __restrict__ sk, const unsigned short* __restrict__ vtT,
        float* __restrict__ attn2, float* __restrict__ pp, float* __restrict__ zb) {
    __shared__ __align__(16) unsigned short vlds[2][8192];  // 32 KB
    __shared__ __align__(16) signed char klds[8192];        // 8 KB
    __shared__ __align__(16) unsigned short plds[4096];     // 8 KB wave-private
    int bx = blockIdx.x, hp = blockIdx.y;
    int qs = 63 - (bx >> 1), c = bx & 1;
    int qb = qs >> 1;                    // 64-row tile index (for pp/zb indexing)
    int q0s = qs * 32;
    int hsp = (qb + 2) >> 1;
    int kb0 = c ? hsp : 0;
    int kb1 = c ? (qb + 1) : hsp;
    int tid = threadIdx.x, w = tid >> 6, l = tid & 63;
    int lrow = l & 15, lg = l >> 4;
    int hh = hp * 2 + (w >> 1);          // this wave's head
    int wrow = (w & 1) * 16;             // row offset within the 32-row sub-tile
    int rrb = (qs & 1) * 32 + wrow;      // row offset within the 64-row tile

    if (kb0 >= kb1) {                    // qb==0 (qs 0,1), c==1: sentinel
        if (lrow == 0) {
            float2* zb2 = (float2*)zb;
            size_t z = (((size_t)hh * 32 + qb) * 2 + c) * 64;
#pragma unroll
            for (int reg = 0; reg < 4; ++reg)
                zb2[z + rrb + lg * 4 + reg] = make_float2(-1e30f, 0.f);
        }
        return;
    }

    const signed char* qt = q_i8 + (size_t)hh * (SEQ * 128)
                          + ((size_t)((qs * 2 + (w & 1)) * 2) << 10) + l * 16;
    v4i qf0 = *(const v4i*)(qt), qf1 = *(const v4i*)(qt + 1024);
    float4 s4 = *(const float4*)(sq + (size_t)hh * SEQ + q0s + wrow + lg * 4);
    float sqr[4] = {s4.x, s4.y, s4.z, s4.w};

    const signed char* kbase = k_i8 + (size_t)hp * (SEQ * 128);
    const float* skb = sk + (size_t)hp * SEQ;
    const unsigned short* vt = vtT + (size_t)hp * (SEQ * 128);

    auto issueV = [&](int kb) {     // 4 ASYNC16 / wave into vlds[kb&1]
        unsigned short* vb = &vlds[kb & 1][0];
#pragma unroll
        for (int a = 0; a < 4; ++a) {
            int fv = a * 4 + w;
            ASYNC16(vt + (size_t)kb * 8192 + fv * 512 + l * 8, vb + fv * 512);
        }
    };
    auto issueK = [&](int kb) {     // 2 ASYNC16 / wave into klds
#pragma unroll
        for (int a = 0; a < 2; ++a) {
            int f = a * 4 + w;
            ASYNC16(kbase + ((size_t)(kb * 8 + f) << 10) + l * 16, klds + f * 1024);
        }
    };

    v4f acc[8];
#pragma unroll
    for (int jd = 0; jd < 8; ++jd) acc[jd] = (v4f){0.f, 0.f, 0.f, 0.f};
    float zt[4] = {0.f, 0.f, 0.f, 0.f};
    float mr[4];
#pragma unroll
    for (int r = 0; r < 4; ++r) mr[r] = -1e30f;

    issueK(kb0);
    issueV(kb0);
    asm volatile("s_waitcnt vmcnt(0)" ::: "memory");
    __builtin_amdgcn_s_barrier();

    for (int kb = kb0; kb < kb1; ++kb) {
        int k0 = kb * 64;
        if (kb + 1 < kb1) issueV(kb + 1);
        v4i ka[8];
#pragma unroll
        for (int f = 0; f < 8; ++f)
            ka[f] = *(const v4i*)(klds + f * 1024 + l * 16);
        float skc[4];
#pragma unroll
        for (int j = 0; j < 4; ++j) skc[j] = skb[k0 + j * 16 + lrow];
        v4i sci[4];
        __builtin_amdgcn_s_setprio(1);
#pragma unroll
        for (int j = 0; j < 4; ++j) {
            v4i z = {0, 0, 0, 0};
            v4i t0 = __builtin_amdgcn_mfma_i32_16x16x64_i8(qf0, ka[j * 2], z, 0, 0, 0);
            sci[j] = __builtin_amdgcn_mfma_i32_16x16x64_i8(qf1, ka[j * 2 + 1], t0, 0, 0, 0);
        }
        __builtin_amdgcn_s_setprio(0);
        // all waves' klds reads complete (MFMA forced lgkm wait) -> safe to refill
        __builtin_amdgcn_s_barrier();
        if (kb + 1 < kb1) issueK(kb + 1);       // overlaps softmax + PV below
        // wave-uniform: is this K-tile fully below the causal diagonal for this wave?
        bool fullt = (k0 + 63 <= q0s + wrow);
        float sv[4][4];
        float tm[4];
#pragma unroll
        for (int reg = 0; reg < 4; ++reg) tm[reg] = -1e30f;
        if (fullt) {
#pragma unroll
            for (int reg = 0; reg < 4; ++reg)
#pragma unroll
                for (int j = 0; j < 4; ++j) {
                    float ss = skc[j] * SM_SCALE;
                    sv[reg][j] = ((float)sci[j][reg] * sqr[reg]) * ss;
                    tm[reg] = fmaxf(tm[reg], sv[reg][j]);
                }
        } else {
#pragma unroll
            for (int reg = 0; reg < 4; ++reg) {
                int r = q0s + wrow + lg * 4 + reg;
#pragma unroll
                for (int j = 0; j < 4; ++j) {
                    int cc = j * 16 + lrow;
                    bool ok = (k0 + cc <= r);
                    float ss = skc[j] * SM_SCALE;
                    sv[reg][j] = ok ? ((float)sci[j][reg] * sqr[reg]) * ss : -1e30f;
                    tm[reg] = fmaxf(tm[reg], sv[reg][j]);
                }
            }
        }
#pragma unroll
        for (int reg = 0; reg < 4; ++reg) {
#pragma unroll
            for (int mask = 1; mask <= 8; mask <<= 1)
                tm[reg] = fmaxf(tm[reg], __shfl_xor(tm[reg], mask));
        }
        float ef[4];
#pragma unroll
        for (int reg = 0; reg < 4; ++reg) {
            float mn = fmaxf(mr[reg], tm[reg]);
            ef[reg] = __expf(mr[reg] - mn);
            mr[reg] = mn;
            zt[reg] *= ef[reg];
        }
        v4f efv = {ef[0], ef[1], ef[2], ef[3]};
#pragma unroll
        for (int jd = 0; jd < 8; ++jd) acc[jd] *= efv;
        if (fullt) {
#pragma unroll
            for (int reg = 0; reg < 4; ++reg) {
                int rq = lg * 4 + reg;
#pragma unroll
                for (int j = 0; j < 4; ++j) {
                    int cc = j * 16 + lrow;
                    float e = __expf(sv[reg][j] - mr[reg]);
                    zt[reg] += e;
                    float pd = fminf(rintf(127.0f * e), 127.f);
                    plds[(w * 2 + (cc >> 5)) * 512 + (rq + 16 * ((cc >> 3) & 3)) * 8 + (cc & 7)] =
                        f2h_bits(pd);
                }
            }
        } else {
#pragma unroll
            for (int reg = 0; reg < 4; ++reg) {
                int rq = lg * 4 + reg;
#pragma unroll
                for (int j = 0; j < 4; ++j) {
                    int cc = j * 16 + lrow;
                    float pd = 0.f;
                    float s = sv[reg][j];
                    if (s > -5e29f) {
                        float e = __expf(s - mr[reg]);
                        zt[reg] += e;
                        pd = fminf(rintf(127.0f * e), 127.f);
                    }
                    plds[(w * 2 + (cc >> 5)) * 512 + (rq + 16 * ((cc >> 3) & 3)) * 8 + (cc & 7)] =
                        f2h_bits(pd);
                }
            }
        }
        v8h pf0 = *(const v8h*)(plds + (w * 2 + 0) * 512 + l * 8);
        v8h pf1 = *(const v8h*)(plds + (w * 2 + 1) * 512 + l * 8);
        const unsigned short* vb = &vlds[kb & 1][0];
        __builtin_amdgcn_s_setprio(1);
#pragma unroll
        for (int jd = 0; jd < 8; ++jd) {
            v8h vh0 = *(const v8h*)(vb + (jd * 2 + 0) * 512 + l * 8);
            v8h vh1 = *(const v8h*)(vb + (jd * 2 + 1) * 512 + l * 8);
            v4f t = acc[jd];
            t = __builtin_amdgcn_mfma_f32_16x16x32_f16(pf0, vh0, t, 0, 0, 0);
            t = __builtin_amdgcn_mfma_f32_16x16x32_f16(pf1, vh1, t, 0, 0, 0);
            acc[jd] = t;
        }
        __builtin_amdgcn_s_setprio(0);
        // V(kb+1) + K(kb+1) were issued >=1 compute-phase ago: mostly-free wait
        asm volatile("s_waitcnt vmcnt(0)" ::: "memory");
        __builtin_amdgcn_s_barrier();
    }
#pragma unroll
    for (int reg = 0; reg < 4; ++reg) {
#pragma unroll
        for (int mask = 1; mask <= 8; mask <<= 1)
            zt[reg] += __shfl_xor(zt[reg], mask);
    }
    if (c == 0) {
#pragma unroll
        for (int jd = 0; jd < 8; ++jd)
#pragma unroll
            for (int reg = 0; reg < 4; ++reg) {
                int r = q0s + wrow + lg * 4 + reg;
                attn2[(size_t)r * DMODEL + hh * HDIM + jd * 16 + lrow] = acc[jd][reg];
            }
    } else {
#pragma unroll
        for (int jd = 0; jd < 8; ++jd)
#pragma unroll
            for (int reg = 0; reg < 4; ++reg) {
                int rr = rrb + lg * 4 + reg;
                pp[(((size_t)hh * 32 + qb) * 64 + rr) * 128 + jd * 16 + lrow] = acc[jd][reg];
            }
    }
    if (lrow == 0) {
        float2* zb2 = (float2*)zb;
        size_t z = (((size_t)hh * 32 + qb) * 2 + c) * 64;
#pragma unroll
        for (int reg = 0; reg < 4; ++reg)
            zb2[z + rrb + lg * 4 + reg] = make_float2(mr[reg], zt[reg]);
    }
}

extern "C" void kernel_launch(void* const* d_in, const int* in_sizes, int n_in,
                              void* d_out, int out_size, void* d_ws, size_t ws_size,
                              hipStream_t stream) {
    (void)in_sizes; (void)n_in; (void)out_size; (void)ws_size;
    const float* hidden = (const float*)d_in[0];
    const float* Wq = (const float*)d_in[1];
    const float* Wk = (const float*)d_in[2];
    const float* Wv = (const float*)d_in[3];
    const float* Wo = (const float*)d_in[4];
    const float* qw = (const float*)d_in[5];
    const float* kw = (const float*)d_in[6];
    const int* pos = (const int*)d_in[7];
    float* out = (float*)d_out;
    char* ws = (char*)d_ws;

    const size_t MB = 1024 * 1024;
    signed char* x_i8  = (signed char*)(ws);            // 16 MB tiled i8 block (x,wq,wk,wv,wo)
    signed char* wq_i8 = (signed char*)(ws + 4 * MB);
    signed char* wo_i8 = (signed char*)(ws + 12 * MB);
    signed char* q_i8  = (signed char*)(ws + 16 * MB);  // 4 MB (attn-tiled)
    signed char* k_i8  = (signed char*)(ws + 20 * MB);  // 2 MB (attn-tiled)
    float* sx  = (float*)(ws + 22 * MB);                // scales
    float* swq = sx + 2048;
    float* swo = sx + 6144;
    float* sq  = sx + 8192;                             // 16*2048
    float* sk  = sq + NH * SEQ;                         // 8*2048
    float* sa  = sk + NKV * SEQ;                        // 2048
    float* ct  = (float*)(ws + 22 * MB + 512 * 1024);   // 512 KB
    float* st  = (float*)(ws + 22 * MB + 1024 * 1024);  // 512 KB
    unsigned short* vtT = (unsigned short*)(ws + 24 * MB); // 4 MB
    float* zb    = (float*)(ws + 28 * MB);              // 512 KB (float2 m,Z per row/chunk)
    float* attn2 = (float*)(ws + 30 * MB);              // 16 MB (chunk-0 raw accs)
    float* pp    = (float*)(ws + 46 * MB);              // 16 MB (chunk-1 raw accs)
    signed char* a_i8 = x_i8;

    quant_rope_k<<<1024, 256, 0, stream>>>(hidden, Wq, Wk, Wv, Wo, pos, x_i8, sx, ct, st);

    gemm_qkv_k<<<dim3(32, 16), 256, 0, stream>>>(x_i8, sx, wq_i8, swq, qw, kw, ct, st,
                                                 q_i8, sq, k_i8, sk, vtT);

    attn_k<<<dim3(128, 8), 256, 0, stream>>>(q_i8, sq, k_i8, sk, vtT, attn2, pp, zb);

    row_quant_red_k<<<128, 256, 0, stream>>>(attn2, pp, zb, a_i8, sa);
    gemm_o_k<<<dim3(32, 16), 256, 0, stream>>>(a_i8, sa, wo_i8, swo, out, 2048, 2048, 2048);
}